// Round 1
// baseline (214.249 us; speedup 1.0000x reference)
//
#include <hip/hip_runtime.h>
#include <math.h>

#define N 4096
#define D 64
#define CH 16

// ---------------- Kernel A: per-row scale + M = linear(msg or task) ----------------
__global__ __launch_bounds__(256) void prep_kernel(
    const float* __restrict__ embed,
    const float* __restrict__ degd, const float* __restrict__ degt,
    const float* __restrict__ W1, const float* __restrict__ b1,
    const float* __restrict__ W2, const float* __restrict__ b2,
    const float* __restrict__ W3, const float* __restrict__ b3,
    float* __restrict__ scale, float* __restrict__ Mbuf)
{
    const int rel = blockIdx.y;
    const float* W  = (rel == 0) ? W1 : (rel == 1 ? W2 : W3);
    const float* bb = (rel == 0) ? b1 : (rel == 1 ? b2 : b3);
    __shared__ float Wl[D][D + 1];   // pad -> (d+k)%32 banks, conflict-free
    __shared__ float xr[4][D];
    const int tid = threadIdx.x;
    for (int idx = tid; idx < D * D; idx += 256)
        Wl[idx >> 6][idx & 63] = W[idx];
    const int w = tid >> 6, d = tid & 63;
    const int i = blockIdx.x * 4 + w;

    float msg, term, xsrc, dga, dgb;
    if (rel == 0) {
        float s = embed[(size_t)i * D + d];
        msg = s + s * s; term = s * msg; xsrc = msg;
        dga = degd[i]; dgb = degd[i];
    } else if (rel == 1) {
        float s = embed[(size_t)i * D + d];
        float t = embed[(size_t)(N + i) * D + d];
        msg = t + s * t; term = s * msg; xsrc = msg;
        dga = degd[i]; dgb = degt[i];
    } else {
        float t = embed[(size_t)(N + i) * D + d];
        msg = t + t * t; term = t * msg; xsrc = t;   // similar uses linear(task)!
        dga = degt[i]; dgb = degt[i];
    }
    float dot = term;
    #pragma unroll
    for (int m = 1; m < 64; m <<= 1) dot += __shfl_xor(dot, m);
    if (d == 0)
        scale[rel * N + i] = dot / (sqrtf(dga * dgb + 1e-8f) * 8.0f);  // sqrt(D)=8

    xr[w][d] = xsrc;
    __syncthreads();
    float o = bb[d];
    #pragma unroll 8
    for (int k = 0; k < D; ++k) o += xr[w][k] * Wl[d][k];
    Mbuf[(size_t)(rel * N + i) * D + d] = o;
}

// ------------- Kernel B: fused online-softmax x (att @ M), per-wave partials -------------
// grid (64 rowgroups, 3 rels, nslice j-slices), block = 1 wave (64 threads).
// Each wave: 64 rows x 64 cols over jlen columns; lane tile 8x8.
__global__ __launch_bounds__(64, 3) void attn_kernel(
    const float* __restrict__ S0, const float* __restrict__ S1, const float* __restrict__ S2,
    const float* __restrict__ scale, const float* __restrict__ Mbuf,
    float* __restrict__ Up, float* __restrict__ mp, float* __restrict__ lp,
    int nslice)
{
    const int rg = blockIdx.x, rel = blockIdx.y, sl = blockIdx.z;
    const float* S   = (rel == 0) ? S0 : (rel == 1 ? S1 : S2);
    const float* Mr  = Mbuf + (size_t)rel * N * D;
    const float* scl = scale + rel * N;
    const int lane = threadIdx.x;
    const int jlen = N / nslice;
    const int j0s  = sl * jlen;

    __shared__ float E[64][CH + 1];   // e values, stride 17 -> (r+k)%32 banks
    __shared__ float Ml[CH][68];      // M chunk, stride 68 (16B-aligned rows)
    __shared__ float mS[64], lS[64], aS[64];

    mS[lane] = -INFINITY;
    lS[lane] = 0.f;

    float acc[8][8];
    #pragma unroll
    for (int u = 0; u < 8; ++u)
        #pragma unroll
        for (int v = 0; v < 8; ++v) acc[u][v] = 0.f;

    const int r4 = lane >> 4, jl = lane & 15;          // e-compute mapping
    const int r0 = (lane & 7) * 8, c0 = (lane >> 3) * 8; // FMA mapping (8 rows x 8 cols)
    const int rowbase = rg * 64;
    const int mrow = lane >> 4, mcol = (lane & 15) * 4;  // M staging mapping

    for (int jc = 0; jc < jlen; jc += CH) {
        const int j0 = j0s + jc;

        // 1) issue all 16 score loads up front (latency)
        float sv[16];
        #pragma unroll
        for (int p = 0; p < 16; ++p)
            sv[p] = S[(size_t)(rowbase + p * 4 + r4) * N + j0 + jl];
        const float myscale = scl[j0 + jl];

        // 2) stage M chunk [16][64] into LDS
        #pragma unroll
        for (int p = 0; p < 4; ++p) {
            const float4 v = *reinterpret_cast<const float4*>(
                &Mr[(size_t)(j0 + p * 4 + mrow) * D + mcol]);
            *reinterpret_cast<float4*>(&Ml[p * 4 + mrow][mcol]) = v;
        }

        // 3) e-compute: online max / sum / alpha, e -> LDS
        #pragma unroll 4
        for (int p = 0; p < 16; ++p) {
            const int i = p * 4 + r4;
            const float logit = sv[p] * myscale;
            float cm = logit;
            cm = fmaxf(cm, __shfl_xor(cm, 1));
            cm = fmaxf(cm, __shfl_xor(cm, 2));
            cm = fmaxf(cm, __shfl_xor(cm, 4));
            cm = fmaxf(cm, __shfl_xor(cm, 8));
            const float mo = mS[i];
            const float mn = fmaxf(mo, cm);
            const float al = __expf(mo - mn);     // first chunk: exp(-inf)=0
            const float e  = __expf(logit - mn);
            float ss = e;
            ss += __shfl_xor(ss, 1);
            ss += __shfl_xor(ss, 2);
            ss += __shfl_xor(ss, 4);
            ss += __shfl_xor(ss, 8);
            if (jl == 0) { mS[i] = mn; aS[i] = al; lS[i] = lS[i] * al + ss; }
            E[i][jl] = e;
        }
        __syncthreads();

        // 4) rescale + 8x8 register-tiled FMA over the chunk
        float av[8];
        #pragma unroll
        for (int u = 0; u < 8; ++u) av[u] = aS[r0 + u];
        #pragma unroll
        for (int u = 0; u < 8; ++u)
            #pragma unroll
            for (int v = 0; v < 8; ++v) acc[u][v] *= av[u];

        #pragma unroll 2
        for (int k = 0; k < CH; ++k) {
            const float4 bv0 = *reinterpret_cast<const float4*>(&Ml[k][c0]);
            const float4 bv1 = *reinterpret_cast<const float4*>(&Ml[k][c0 + 4]);
            float b[8] = {bv0.x, bv0.y, bv0.z, bv0.w, bv1.x, bv1.y, bv1.z, bv1.w};
            float a[8];
            #pragma unroll
            for (int u = 0; u < 8; ++u) a[u] = E[r0 + u][k];
            #pragma unroll
            for (int u = 0; u < 8; ++u)
                #pragma unroll
                for (int v = 0; v < 8; ++v)
                    acc[u][v] = fmaf(a[u], b[v], acc[u][v]);
        }
        __syncthreads();
    }

    // 5) write flash partials
    const size_t pbase = (size_t)((rel * 64 + rg) * nslice + sl);
    float* up = Up + pbase * 4096;
    #pragma unroll
    for (int u = 0; u < 8; ++u) {
        float4 t0 = make_float4(acc[u][0], acc[u][1], acc[u][2], acc[u][3]);
        float4 t1 = make_float4(acc[u][4], acc[u][5], acc[u][6], acc[u][7]);
        *reinterpret_cast<float4*>(&up[(r0 + u) * 64 + c0])     = t0;
        *reinterpret_cast<float4*>(&up[(r0 + u) * 64 + c0 + 4]) = t1;
    }
    mp[pbase * 64 + lane] = mS[lane];
    lp[pbase * 64 + lane] = lS[lane];
}

// ---------------- Kernel C: combine partials + residual + linear(W3) + leaky-relu ----------------
__device__ __forceinline__ float combine_row(
    const float* __restrict__ Up, const float* __restrict__ mp, const float* __restrict__ lp,
    int rel, int i, int d, int nslice)
{
    const int rg = i >> 6, r = i & 63;
    const int base = (rel * 64 + rg) * nslice;
    float mt = -INFINITY;
    for (int p = 0; p < nslice; ++p) mt = fmaxf(mt, mp[(base + p) * 64 + r]);
    float lt = 0.f, u = 0.f;
    for (int p = 0; p < nslice; ++p) {
        const float wgt = __expf(mp[(base + p) * 64 + r] - mt);
        lt += lp[(base + p) * 64 + r] * wgt;
        u  += Up[(size_t)(base + p) * 4096 + r * 64 + d] * wgt;
    }
    return u / lt;   // lt >= 1 for the max slice -> no div0
}

__global__ __launch_bounds__(256) void final_kernel(
    const float* __restrict__ embed,
    const float* __restrict__ Up, const float* __restrict__ mp, const float* __restrict__ lp,
    const float* __restrict__ W3, const float* __restrict__ b3,
    float* __restrict__ out, int nslice)
{
    __shared__ float Wl[D][D + 1];
    __shared__ float xs[4][D];
    const int tid = threadIdx.x;
    for (int idx = tid; idx < D * D; idx += 256)
        Wl[idx >> 6][idx & 63] = W3[idx];
    const int w = tid >> 6, d = tid & 63;
    const int g = blockIdx.x * 4 + w;   // 0..8191; uniform per block (4 rows)

    float x = embed[(size_t)g * D + d];
    if (g < N) {
        x += combine_row(Up, mp, lp, 0, g, d, nslice);
        x += combine_row(Up, mp, lp, 1, g, d, nslice);
    } else {
        x += combine_row(Up, mp, lp, 2, g - N, d, nslice);
    }
    xs[w][d] = x;
    __syncthreads();
    float o = b3[d];
    #pragma unroll 8
    for (int k = 0; k < D; ++k) o += xs[w][k] * Wl[d][k];
    o = (o > 0.f) ? o : 0.2f * o;
    out[(size_t)g * D + d] = o;
}

extern "C" void kernel_launch(void* const* d_in, const int* in_sizes, int n_in,
                              void* d_out, int out_size, void* d_ws, size_t ws_size,
                              hipStream_t stream)
{
    const float* embed = (const float*)d_in[0];
    // d_in[1..3] = adj_* (unused by the reference)
    const float* Sc   = (const float*)d_in[4];
    const float* Si   = (const float*)d_in[5];
    const float* Ss   = (const float*)d_in[6];
    const float* degd = (const float*)d_in[7];
    const float* degt = (const float*)d_in[8];
    const float* W1 = (const float*)d_in[9];
    const float* b1 = (const float*)d_in[10];
    const float* W2 = (const float*)d_in[11];
    const float* b2 = (const float*)d_in[12];
    const float* W3 = (const float*)d_in[13];
    const float* b3 = (const float*)d_in[14];
    float* out = (float*)d_out;

    // pick nslice (j-split) to fit the workspace; 16 -> ~55 MB
    int nslice = 16;
    while (nslice > 1) {
        size_t need_floats = (size_t)798720 + (size_t)nslice * (24576 + 786432);
        if (need_floats * 4 <= ws_size) break;
        nslice >>= 1;
    }
    float* ws    = (float*)d_ws;
    float* scale = ws;                                   // 3*N
    float* Mbuf  = ws + 12288;                           // 3*N*D
    float* mp    = Mbuf + 786432;                        // 3*64*nslice*64
    float* lp    = mp + (size_t)3 * 64 * nslice * 64;
    float* Up    = lp + (size_t)3 * 64 * nslice * 64;    // 3*64*nslice*4096

    prep_kernel<<<dim3(N / 4, 3), 256, 0, stream>>>(
        embed, degd, degt, W1, b1, W2, b2, W3, b3, scale, Mbuf);
    attn_kernel<<<dim3(64, 3, nslice), 64, 0, stream>>>(
        Sc, Si, Ss, scale, Mbuf, Up, mp, lp, nslice);
    final_kernel<<<dim3(2 * N / 4), 256, 0, stream>>>(
        embed, Up, mp, lp, W3, b3, out, nslice);
}

// Round 2
// 187.556 us; speedup vs baseline: 1.1423x; 1.1423x over previous
//
#include <hip/hip_runtime.h>
#include <hip/hip_bf16.h>
#include <math.h>

#define N 4096
#define D 64
#define CH 16

// ---------------- Kernel A: per-row scale + M = linear(msg or task) ----------------
__global__ __launch_bounds__(256) void prep_kernel(
    const float* __restrict__ embed,
    const float* __restrict__ degd, const float* __restrict__ degt,
    const float* __restrict__ W1, const float* __restrict__ b1,
    const float* __restrict__ W2, const float* __restrict__ b2,
    const float* __restrict__ W3, const float* __restrict__ b3,
    float* __restrict__ scale, float* __restrict__ Mbuf)
{
    const int rel = blockIdx.y;
    const float* W  = (rel == 0) ? W1 : (rel == 1 ? W2 : W3);
    const float* bb = (rel == 0) ? b1 : (rel == 1 ? b2 : b3);
    __shared__ float Wl[D][D + 1];
    __shared__ float xr[4][D];
    const int tid = threadIdx.x;
    for (int idx = tid; idx < D * D; idx += 256)
        Wl[idx >> 6][idx & 63] = W[idx];
    const int w = tid >> 6, d = tid & 63;
    const int i = blockIdx.x * 4 + w;

    float msg, term, xsrc, dga, dgb;
    if (rel == 0) {
        float s = embed[(size_t)i * D + d];
        msg = s + s * s; term = s * msg; xsrc = msg;
        dga = degd[i]; dgb = degd[i];
    } else if (rel == 1) {
        float s = embed[(size_t)i * D + d];
        float t = embed[(size_t)(N + i) * D + d];
        msg = t + s * t; term = s * msg; xsrc = msg;
        dga = degd[i]; dgb = degt[i];
    } else {
        float t = embed[(size_t)(N + i) * D + d];
        msg = t + t * t; term = t * msg; xsrc = t;   // similar uses linear(task)!
        dga = degt[i]; dgb = degt[i];
    }
    float dot = term;
    #pragma unroll
    for (int mm = 1; mm < 64; mm <<= 1) dot += __shfl_xor(dot, mm);
    if (d == 0)
        scale[rel * N + i] = dot / (sqrtf(dga * dgb + 1e-8f) * 8.0f);  // sqrt(D)=8

    xr[w][d] = xsrc;
    __syncthreads();
    float o = bb[d];
    #pragma unroll 8
    for (int k = 0; k < D; ++k) o += xr[w][k] * Wl[d][k];
    Mbuf[(size_t)(rel * N + i) * D + d] = o;
}

// ------------- Kernel B: fused online-softmax x (att @ M), per-wave partials -------------
// grid (64 rowgroups, 3 rels, nslice j-slices), block = 1 wave (64 threads).
// Row-per-lane softmax (no shuffles, m/l in regs); register double-buffer prefetch.
__global__ __launch_bounds__(64, 3) void attn_kernel(
    const float* __restrict__ S0, const float* __restrict__ S1, const float* __restrict__ S2,
    const float* __restrict__ scale, const float* __restrict__ Mbuf,
    __hip_bfloat16* __restrict__ Up, float* __restrict__ mp, float* __restrict__ lp,
    int nslice)
{
    const int rg = blockIdx.x, rel = blockIdx.y, sl = blockIdx.z;
    const float* S   = (rel == 0) ? S0 : (rel == 1 ? S1 : S2);
    const float* Mr  = Mbuf + (size_t)rel * N * D;
    const float* scl = scale + rel * N;
    const int lane = threadIdx.x;
    const int jlen = N / nslice;
    const int j0s  = sl * jlen;

    __shared__ float E[64][CH + 1];   // stride 17: 2-way on reads/writes = free
    __shared__ float Ml[CH][D];       // unpadded: read/write patterns are 2-way = free
    __shared__ float scl_l[512];      // jlen <= 512
    __shared__ float aS[64];

    for (int k = lane; k < jlen; k += 64) scl_l[k] = scl[j0s + k];

    const float* Srow = S + (size_t)(rg * 64 + lane) * N + j0s;
    const int mr = lane >> 4, mc = (lane & 15) * 4;       // M staging mapping
    const int r0 = (lane & 7) * 8, c0 = (lane >> 3) * 8;  // FMA 8x8 tile mapping

    float m = -INFINITY, l = 0.f;
    float acc[8][8];
    #pragma unroll
    for (int u = 0; u < 8; ++u)
        #pragma unroll
        for (int v = 0; v < 8; ++v) acc[u][v] = 0.f;

    // prologue: prefetch chunk 0 into registers
    float4 sv[4], mv[4];
    #pragma unroll
    for (int g = 0; g < 4; ++g) {
        sv[g] = *reinterpret_cast<const float4*>(Srow + g * 4);
        mv[g] = *reinterpret_cast<const float4*>(&Mr[(size_t)(j0s + g * 4 + mr) * D + mc]);
    }
    __syncthreads();   // scl_l visible

    for (int jc = 0; jc < jlen; jc += CH) {
        // ---- phase 1: stage M(cur), e-compute(cur) ----
        #pragma unroll
        for (int g = 0; g < 4; ++g)
            *reinterpret_cast<float4*>(&Ml[g * 4 + mr][mc]) = mv[g];

        float lg[16];
        #pragma unroll
        for (int g = 0; g < 4; ++g) {
            lg[4 * g + 0] = sv[g].x * scl_l[jc + 4 * g + 0];
            lg[4 * g + 1] = sv[g].y * scl_l[jc + 4 * g + 1];
            lg[4 * g + 2] = sv[g].z * scl_l[jc + 4 * g + 2];
            lg[4 * g + 3] = sv[g].w * scl_l[jc + 4 * g + 3];
        }
        float cmax = lg[0];
        #pragma unroll
        for (int k = 1; k < 16; ++k) cmax = fmaxf(cmax, lg[k]);
        const float mn = fmaxf(m, cmax);
        const float al = __expf(m - mn);      // first chunk: exp(-inf)=0
        float s = 0.f;
        #pragma unroll
        for (int k = 0; k < 16; ++k) {
            const float e = __expf(lg[k] - mn);
            E[lane][k] = e;
            s += e;
        }
        l = l * al + s;
        m = mn;
        aS[lane] = al;

        // ---- issue next-chunk loads (hidden under the FMA phase) ----
        if (jc + CH < jlen) {
            #pragma unroll
            for (int g = 0; g < 4; ++g) {
                sv[g] = *reinterpret_cast<const float4*>(Srow + jc + CH + g * 4);
                mv[g] = *reinterpret_cast<const float4*>(
                    &Mr[(size_t)(j0s + jc + CH + g * 4 + mr) * D + mc]);
            }
        }
        __syncthreads();

        // ---- phase 2: rescale + 8x8 register-tiled FMA ----
        float av[8];
        #pragma unroll
        for (int u = 0; u < 8; ++u) av[u] = aS[r0 + u];
        #pragma unroll
        for (int u = 0; u < 8; ++u)
            #pragma unroll
            for (int v = 0; v < 8; ++v) acc[u][v] *= av[u];

        #pragma unroll 4
        for (int k = 0; k < CH; ++k) {
            const float4 bv0 = *reinterpret_cast<const float4*>(&Ml[k][c0]);
            const float4 bv1 = *reinterpret_cast<const float4*>(&Ml[k][c0 + 4]);
            float b[8] = {bv0.x, bv0.y, bv0.z, bv0.w, bv1.x, bv1.y, bv1.z, bv1.w};
            float a[8];
            #pragma unroll
            for (int u = 0; u < 8; ++u) a[u] = E[r0 + u][k];
            #pragma unroll
            for (int u = 0; u < 8; ++u)
                #pragma unroll
                for (int v = 0; v < 8; ++v)
                    acc[u][v] = fmaf(a[u], b[v], acc[u][v]);
        }
        __syncthreads();
    }

    // ---- write flash partials (U in bf16) ----
    const size_t pbase = (size_t)((rel * 64 + rg) * nslice + sl);
    __hip_bfloat16* up = Up + pbase * 4096;
    #pragma unroll
    for (int u = 0; u < 8; ++u) {
        union { __hip_bfloat16 h[8]; uint4 u4; } t;
        #pragma unroll
        for (int v = 0; v < 8; ++v) t.h[v] = __float2bfloat16(acc[u][v]);
        *reinterpret_cast<uint4*>(&up[(r0 + u) * 64 + c0]) = t.u4;
    }
    mp[pbase * 64 + lane] = m;
    lp[pbase * 64 + lane] = l;
}

// ---------------- Kernel C: combine partials + residual + linear(W3) + leaky-relu ----------------
__device__ __forceinline__ float combine_row(
    const __hip_bfloat16* __restrict__ Up, const float* __restrict__ mp,
    const float* __restrict__ lp, int rel, int i, int d, int nslice)
{
    const int rg = i >> 6, r = i & 63;
    const int base = (rel * 64 + rg) * nslice;
    float mt = -INFINITY;
    for (int p = 0; p < nslice; ++p) mt = fmaxf(mt, mp[(base + p) * 64 + r]);
    float lt = 0.f, u = 0.f;
    for (int p = 0; p < nslice; ++p) {
        const float wgt = __expf(mp[(base + p) * 64 + r] - mt);
        lt += lp[(base + p) * 64 + r] * wgt;
        u  += __bfloat162float(Up[(size_t)(base + p) * 4096 + r * 64 + d]) * wgt;
    }
    return u / lt;   // lt >= 1 for the max slice -> no div0
}

__global__ __launch_bounds__(256) void final_kernel(
    const float* __restrict__ embed,
    const __hip_bfloat16* __restrict__ Up, const float* __restrict__ mp,
    const float* __restrict__ lp,
    const float* __restrict__ W3, const float* __restrict__ b3,
    float* __restrict__ out, int nslice)
{
    __shared__ float Wl[D][D + 1];
    __shared__ float xs[4][D];
    const int tid = threadIdx.x;
    for (int idx = tid; idx < D * D; idx += 256)
        Wl[idx >> 6][idx & 63] = W3[idx];
    const int w = tid >> 6, d = tid & 63;
    const int g = blockIdx.x * 4 + w;   // 0..8191

    float x = embed[(size_t)g * D + d];
    if (g < N) {
        x += combine_row(Up, mp, lp, 0, g, d, nslice);
        x += combine_row(Up, mp, lp, 1, g, d, nslice);
    } else {
        x += combine_row(Up, mp, lp, 2, g - N, d, nslice);
    }
    xs[w][d] = x;
    __syncthreads();
    float o = b3[d];
    #pragma unroll 8
    for (int k = 0; k < D; ++k) o += xs[w][k] * Wl[d][k];
    o = (o > 0.f) ? o : 0.2f * o;
    out[(size_t)g * D + d] = o;
}

extern "C" void kernel_launch(void* const* d_in, const int* in_sizes, int n_in,
                              void* d_out, int out_size, void* d_ws, size_t ws_size,
                              hipStream_t stream)
{
    const float* embed = (const float*)d_in[0];
    // d_in[1..3] = adj_* (unused by the reference)
    const float* Sc   = (const float*)d_in[4];
    const float* Si   = (const float*)d_in[5];
    const float* Ss   = (const float*)d_in[6];
    const float* degd = (const float*)d_in[7];
    const float* degt = (const float*)d_in[8];
    const float* W1 = (const float*)d_in[9];
    const float* b1 = (const float*)d_in[10];
    const float* W2 = (const float*)d_in[11];
    const float* b2 = (const float*)d_in[12];
    const float* W3 = (const float*)d_in[13];
    const float* b3 = (const float*)d_in[14];
    float* out = (float*)d_out;

    // workspace: scale(3N f32) + Mbuf(3ND f32) + per-slice {mp,lp f32, Up bf16}
    const size_t base_bytes = (size_t)(12288 + 786432) * 4;
    const size_t per_slice_bytes = (size_t)24576 * 4 + (size_t)786432 * 2;  // 1.67 MB
    int nslice = 32;
    while (nslice > 8 && base_bytes + (size_t)nslice * per_slice_bytes > ws_size)
        nslice >>= 1;

    float* ws    = (float*)d_ws;
    float* scale = ws;                                    // 3*N f32
    float* Mbuf  = ws + 12288;                            // 3*N*D f32
    float* mp    = Mbuf + 786432;                         // 3*64*nslice*64 f32
    float* lp    = mp + (size_t)12288 * nslice;
    __hip_bfloat16* Up = (__hip_bfloat16*)(lp + (size_t)12288 * nslice);

    prep_kernel<<<dim3(N / 4, 3), 256, 0, stream>>>(
        embed, degd, degt, W1, b1, W2, b2, W3, b3, scale, Mbuf);
    attn_kernel<<<dim3(64, 3, nslice), 64, 0, stream>>>(
        Sc, Si, Ss, scale, Mbuf, Up, mp, lp, nslice);
    final_kernel<<<dim3(2 * N / 4), 256, 0, stream>>>(
        embed, Up, mp, lp, W3, b3, out, nslice);
}

// Round 3
// 92.703 us; speedup vs baseline: 2.3111x; 2.0232x over previous
//
#include <hip/hip_runtime.h>
#include <math.h>

#define N 4096
#define D 64
#define NSLICE 16
#define JLEN 256          // N / NSLICE
#define CH 64             // j-chunk per iteration
#define NCHUNK 4          // JLEN / CH

typedef short bf16x8 __attribute__((ext_vector_type(8)));
typedef float f32x4  __attribute__((ext_vector_type(4)));

__device__ __forceinline__ unsigned short f2bf(float x) {   // RNE f32->bf16
    unsigned int u = __float_as_uint(x);
    u += 0x7FFFu + ((u >> 16) & 1u);
    return (unsigned short)(u >> 16);
}
__device__ __forceinline__ float bf2f(unsigned short h) {
    return __uint_as_float(((unsigned int)h) << 16);
}

// ---------------- Kernel A: per-row scale + Mt[d][j] = bf16(linear(msg)) ----------------
__global__ __launch_bounds__(256) void prep_kernel(
    const float* __restrict__ embed,
    const float* __restrict__ degd, const float* __restrict__ degt,
    const float* __restrict__ W1, const float* __restrict__ b1,
    const float* __restrict__ W2, const float* __restrict__ b2,
    const float* __restrict__ W3, const float* __restrict__ b3,
    float* __restrict__ scale, unsigned short* __restrict__ Mt)
{
    const int rel = blockIdx.y;
    const float* W  = (rel == 0) ? W1 : (rel == 1 ? W2 : W3);
    const float* bb = (rel == 0) ? b1 : (rel == 1 ? b2 : b3);
    __shared__ float Wl[D][D + 1];
    __shared__ float xr[4][D];
    const int tid = threadIdx.x;
    for (int idx = tid; idx < D * D; idx += 256)
        Wl[idx >> 6][idx & 63] = W[idx];
    const int w = tid >> 6, d = tid & 63;
    const int i = blockIdx.x * 4 + w;

    float msg, term, xsrc, dga, dgb;
    if (rel == 0) {
        float s = embed[(size_t)i * D + d];
        msg = s + s * s; term = s * msg; xsrc = msg;
        dga = degd[i]; dgb = degd[i];
    } else if (rel == 1) {
        float s = embed[(size_t)i * D + d];
        float t = embed[(size_t)(N + i) * D + d];
        msg = t + s * t; term = s * msg; xsrc = msg;
        dga = degd[i]; dgb = degt[i];
    } else {
        float t = embed[(size_t)(N + i) * D + d];
        msg = t + t * t; term = t * msg; xsrc = t;   // similar uses linear(task)!
        dga = degt[i]; dgb = degt[i];
    }
    float dot = term;
    #pragma unroll
    for (int mm = 1; mm < 64; mm <<= 1) dot += __shfl_xor(dot, mm);
    if (d == 0)
        scale[rel * N + i] = dot / (sqrtf(dga * dgb + 1e-8f) * 8.0f);  // sqrt(D)=8

    xr[w][d] = xsrc;
    __syncthreads();
    float o = bb[d];
    #pragma unroll 8
    for (int k = 0; k < D; ++k) o += xr[w][k] * Wl[d][k];
    Mt[((size_t)rel * D + d) * N + i] = f2bf(o);   // transposed, bf16
}

// ------------- Kernel B: fused online-softmax x (att @ M) via bf16 MFMA -------------
// grid (64 rowgroups, 3 rels, NSLICE j-slices), block = 256 (4 waves).
// e-phase: 4 lanes/row (quad shuffles). MFMA: wave w owns rows w*16..w*16+15,
// all 64 cols (4 col-tiles), mfma_f32_16x16x32_bf16.
__global__ __launch_bounds__(256, 2) void attn_kernel(
    const float* __restrict__ S0, const float* __restrict__ S1, const float* __restrict__ S2,
    const float* __restrict__ scale, const unsigned short* __restrict__ Mt,
    unsigned short* __restrict__ Up, float* __restrict__ mp, float* __restrict__ lp)
{
    const int rg = blockIdx.x, rel = blockIdx.y, sl = blockIdx.z;
    const float* S = (rel == 0) ? S0 : (rel == 1 ? S1 : S2);
    const unsigned short* Mtr = Mt + (size_t)rel * D * N;
    const int tid = threadIdx.x;
    const int lane = tid & 63, wave = tid >> 6;
    const int row = tid >> 2, q = tid & 3;      // e-phase: 4 lanes per row

    // XOR-swizzled bf16 tiles: row stride 128B = 8 x 16B slots; slot ^= (row&7)
    __shared__ unsigned short E[64 * 64];
    __shared__ unsigned short Ml[64 * 64];
    __shared__ float scl_l[JLEN];
    __shared__ float aS[64];

    scl_l[tid] = scale[rel * N + sl * JLEN + tid];

    const float*          Sp = S   + (size_t)(rg * 64 + row) * N + sl * JLEN + q * 16;
    const unsigned short* Mp = Mtr + (size_t)row * N          + sl * JLEN + q * 16;

    char* Eb = (char*)E;
    char* Mb = (char*)Ml;
    const int sw  = (row & 7) << 4;
    const int ew0 = row * 128 + ((q * 32 +  0) ^ sw);
    const int ew1 = row * 128 + ((q * 32 + 16) ^ sw);

    float m = -INFINITY, l = 0.f;

    const int wbase = wave * 16;
    const int lrow  = lane & 15;   // A-row / B-col / C-col within tile
    const int lk    = lane >> 4;   // k-group / C row-group
    f32x4 acc[4];
    #pragma unroll
    for (int ct = 0; ct < 4; ++ct) {
        acc[ct][0] = 0.f; acc[ct][1] = 0.f; acc[ct][2] = 0.f; acc[ct][3] = 0.f;
    }

    float4 sv[2][4];
    uint4  mtv[2][2];
    #pragma unroll
    for (int g = 0; g < 4; ++g) sv[0][g] = *(const float4*)(Sp + g * 4);
    mtv[0][0] = *(const uint4*)(Mp);
    mtv[0][1] = *(const uint4*)(Mp + 8);
    __syncthreads();   // scl_l visible

    #pragma unroll
    for (int c = 0; c < NCHUNK; ++c) {
        const int cb = c & 1;
        // ---- stage Mt(c) into swizzled LDS ----
        *(uint4*)(Mb + ew0) = mtv[cb][0];
        *(uint4*)(Mb + ew1) = mtv[cb][1];

        // ---- e-phase ----
        const float4 s0 = sv[cb][0], s1 = sv[cb][1], s2 = sv[cb][2], s3 = sv[cb][3];
        const float4 c0 = *(const float4*)&scl_l[c * 64 + q * 16 + 0];
        const float4 c1 = *(const float4*)&scl_l[c * 64 + q * 16 + 4];
        const float4 c2 = *(const float4*)&scl_l[c * 64 + q * 16 + 8];
        const float4 c3 = *(const float4*)&scl_l[c * 64 + q * 16 + 12];
        float lg[16];
        lg[0]=s0.x*c0.x; lg[1]=s0.y*c0.y; lg[2]=s0.z*c0.z; lg[3]=s0.w*c0.w;
        lg[4]=s1.x*c1.x; lg[5]=s1.y*c1.y; lg[6]=s1.z*c1.z; lg[7]=s1.w*c1.w;
        lg[8]=s2.x*c2.x; lg[9]=s2.y*c2.y; lg[10]=s2.z*c2.z; lg[11]=s2.w*c2.w;
        lg[12]=s3.x*c3.x; lg[13]=s3.y*c3.y; lg[14]=s3.z*c3.z; lg[15]=s3.w*c3.w;
        float cmax = lg[0];
        #pragma unroll
        for (int k = 1; k < 16; ++k) cmax = fmaxf(cmax, lg[k]);
        cmax = fmaxf(cmax, __shfl_xor(cmax, 1));
        cmax = fmaxf(cmax, __shfl_xor(cmax, 2));
        const float mn = fmaxf(m, cmax);
        const float al = __expf(m - mn);   // chunk 0: exp(-inf)=0
        float e[16], s = 0.f;
        #pragma unroll
        for (int k = 0; k < 16; ++k) { e[k] = __expf(lg[k] - mn); s += e[k]; }
        s += __shfl_xor(s, 1);
        s += __shfl_xor(s, 2);
        l = l * al + s; m = mn;
        if (q == 0) aS[row] = al;
        union { unsigned short h[8]; uint4 v; } p0, p1;
        #pragma unroll
        for (int k = 0; k < 8; ++k) { p0.h[k] = f2bf(e[k]); p1.h[k] = f2bf(e[8 + k]); }
        *(uint4*)(Eb + ew0) = p0.v;
        *(uint4*)(Eb + ew1) = p1.v;

        // ---- prefetch next chunk (hidden under MFMA + barrier) ----
        if (c + 1 < NCHUNK) {
            const int nb = cb ^ 1;
            #pragma unroll
            for (int g = 0; g < 4; ++g)
                sv[nb][g] = *(const float4*)(Sp + (c + 1) * 64 + g * 4);
            mtv[nb][0] = *(const uint4*)(Mp + (c + 1) * 64);
            mtv[nb][1] = *(const uint4*)(Mp + (c + 1) * 64 + 8);
        }
        __syncthreads();

        // ---- rescale + MFMA ----
        const float av0 = aS[wbase + lk * 4 + 0];
        const float av1 = aS[wbase + lk * 4 + 1];
        const float av2 = aS[wbase + lk * 4 + 2];
        const float av3 = aS[wbase + lk * 4 + 3];
        #pragma unroll
        for (int ct = 0; ct < 4; ++ct) {
            acc[ct][0] *= av0; acc[ct][1] *= av1;
            acc[ct][2] *= av2; acc[ct][3] *= av3;
        }
        #pragma unroll
        for (int ks = 0; ks < 2; ++ks) {
            const int rowA  = wbase + lrow;
            const int slotA = (ks * 4 + lk) ^ (rowA & 7);
            const bf16x8 a  = *(const bf16x8*)(Eb + rowA * 128 + (slotA << 4));
            #pragma unroll
            for (int ct = 0; ct < 4; ++ct) {
                const int colB  = ct * 16 + lrow;
                const int slotB = (ks * 4 + lk) ^ (colB & 7);
                const bf16x8 b  = *(const bf16x8*)(Mb + colB * 128 + (slotB << 4));
                acc[ct] = __builtin_amdgcn_mfma_f32_16x16x32_bf16(a, b, acc[ct], 0, 0, 0);
            }
        }
        __syncthreads();   // before next chunk overwrites E/Ml/aS
    }

    // ---- write flash partials ----
    const size_t pbase = (size_t)((rel * 64 + rg) * NSLICE + sl);
    unsigned short* up = Up + pbase * 4096;
    #pragma unroll
    for (int ct = 0; ct < 4; ++ct)
        #pragma unroll
        for (int r = 0; r < 4; ++r) {
            const int ri = wbase + lk * 4 + r;   // C/D: row=(lane>>4)*4+reg
            up[ri * 64 + ct * 16 + lrow] = f2bf(acc[ct][r]);
        }
    if (q == 0) { mp[pbase * 64 + row] = m; lp[pbase * 64 + row] = l; }
}

// ---------------- Kernel C: combine partials + residual + linear(W3) + leaky-relu ----------------
__device__ __forceinline__ float combine_row(
    const unsigned short* __restrict__ Up, const float* __restrict__ mp,
    const float* __restrict__ lp, int rel, int i, int d)
{
    const int rg = i >> 6, r = i & 63;
    const int base = (rel * 64 + rg) * NSLICE;
    float mt = -INFINITY;
    #pragma unroll 4
    for (int p = 0; p < NSLICE; ++p) mt = fmaxf(mt, mp[(base + p) * 64 + r]);
    float lt = 0.f, u = 0.f;
    #pragma unroll 4
    for (int p = 0; p < NSLICE; ++p) {
        const float wgt = __expf(mp[(base + p) * 64 + r] - mt);
        lt += lp[(base + p) * 64 + r] * wgt;
        u  += bf2f(Up[(size_t)(base + p) * 4096 + r * 64 + d]) * wgt;
    }
    return u / lt;   // lt >= 1 for the max slice -> no div0
}

__global__ __launch_bounds__(256) void final_kernel(
    const float* __restrict__ embed,
    const unsigned short* __restrict__ Up, const float* __restrict__ mp,
    const float* __restrict__ lp,
    const float* __restrict__ W3, const float* __restrict__ b3,
    float* __restrict__ out)
{
    __shared__ float Wl[D][D + 1];
    __shared__ float xs[4][D];
    const int tid = threadIdx.x;
    for (int idx = tid; idx < D * D; idx += 256)
        Wl[idx >> 6][idx & 63] = W3[idx];
    const int w = tid >> 6, d = tid & 63;
    const int g = blockIdx.x * 4 + w;   // 0..8191

    float x = embed[(size_t)g * D + d];
    if (g < N) {
        x += combine_row(Up, mp, lp, 0, g, d);
        x += combine_row(Up, mp, lp, 1, g, d);
    } else {
        x += combine_row(Up, mp, lp, 2, g - N, d);
    }
    xs[w][d] = x;
    __syncthreads();
    float o = b3[d];
    #pragma unroll 8
    for (int k = 0; k < D; ++k) o += xs[w][k] * Wl[d][k];
    o = (o > 0.f) ? o : 0.2f * o;
    out[(size_t)g * D + d] = o;
}

extern "C" void kernel_launch(void* const* d_in, const int* in_sizes, int n_in,
                              void* d_out, int out_size, void* d_ws, size_t ws_size,
                              hipStream_t stream)
{
    const float* embed = (const float*)d_in[0];
    // d_in[1..3] = adj_* (unused by the reference)
    const float* Sc   = (const float*)d_in[4];
    const float* Si   = (const float*)d_in[5];
    const float* Ss   = (const float*)d_in[6];
    const float* degd = (const float*)d_in[7];
    const float* degt = (const float*)d_in[8];
    const float* W1 = (const float*)d_in[9];
    const float* b1 = (const float*)d_in[10];
    const float* W2 = (const float*)d_in[11];
    const float* b2 = (const float*)d_in[12];
    const float* W3 = (const float*)d_in[13];
    const float* b3 = (const float*)d_in[14];
    float* out = (float*)d_out;

    // ws layout (f32 first, 16B-aligned boundaries):
    //   scale: 3*N            = 12288 f32
    //   mp:    3*64*NSLICE*64 = 196608 f32
    //   lp:                     196608 f32
    //   Mt:    3*D*N          = 786432 bf16 (ushort)
    //   Up:    3*64*NSLICE*4096 = 12582912 bf16 (ushort)     total ~28.4 MB
    float* ws    = (float*)d_ws;
    float* scale = ws;
    float* mp    = ws + 12288;
    float* lp    = mp + 196608;
    unsigned short* Mt = (unsigned short*)(lp + 196608);
    unsigned short* Up = Mt + 786432;

    prep_kernel<<<dim3(N / 4, 3), 256, 0, stream>>>(
        embed, degd, degt, W1, b1, W2, b2, W3, b3, scale, Mt);
    attn_kernel<<<dim3(64, 3, NSLICE), 256, 0, stream>>>(
        Sc, Si, Ss, scale, Mt, Up, mp, lp);
    final_kernel<<<dim3(2 * N / 4), 256, 0, stream>>>(
        embed, Up, mp, lp, W3, b3, out);
}

// Round 4
// 85.930 us; speedup vs baseline: 2.4933x; 1.0788x over previous
//
#include <hip/hip_runtime.h>
#include <math.h>

#define N 4096
#define D 64
#define NSLICE 8
#define JLEN 512          // N / NSLICE
#define CH 64             // j-chunk per iteration
#define NCHUNK 8          // JLEN / CH

typedef short bf16x8 __attribute__((ext_vector_type(8)));
typedef float f32x4  __attribute__((ext_vector_type(4)));

__device__ __forceinline__ unsigned short f2bf(float x) {   // RNE f32->bf16
    unsigned int u = __float_as_uint(x);
    u += 0x7FFFu + ((u >> 16) & 1u);
    return (unsigned short)(u >> 16);
}
__device__ __forceinline__ float bf2f(unsigned short h) {
    return __uint_as_float(((unsigned int)h) << 16);
}

// ---------------- Kernel A: per-row scale + Mt[d][j] = bf16(linear(msg)) ----------------
__global__ __launch_bounds__(256) void prep_kernel(
    const float* __restrict__ embed,
    const float* __restrict__ degd, const float* __restrict__ degt,
    const float* __restrict__ W1, const float* __restrict__ b1,
    const float* __restrict__ W2, const float* __restrict__ b2,
    const float* __restrict__ W3, const float* __restrict__ b3,
    float* __restrict__ scale, unsigned short* __restrict__ Mt)
{
    const int rel = blockIdx.y;
    const float* W  = (rel == 0) ? W1 : (rel == 1 ? W2 : W3);
    const float* bb = (rel == 0) ? b1 : (rel == 1 ? b2 : b3);
    __shared__ float Wl[D][D + 1];
    __shared__ float xr[4][D];
    const int tid = threadIdx.x;
    for (int idx = tid; idx < D * D; idx += 256)
        Wl[idx >> 6][idx & 63] = W[idx];
    const int w = tid >> 6, d = tid & 63;
    const int i = blockIdx.x * 4 + w;

    float msg, term, xsrc, dga, dgb;
    if (rel == 0) {
        float s = embed[(size_t)i * D + d];
        msg = s + s * s; term = s * msg; xsrc = msg;
        dga = degd[i]; dgb = degd[i];
    } else if (rel == 1) {
        float s = embed[(size_t)i * D + d];
        float t = embed[(size_t)(N + i) * D + d];
        msg = t + s * t; term = s * msg; xsrc = msg;
        dga = degd[i]; dgb = degt[i];
    } else {
        float t = embed[(size_t)(N + i) * D + d];
        msg = t + t * t; term = t * msg; xsrc = t;   // similar uses linear(task)!
        dga = degt[i]; dgb = degt[i];
    }
    float dot = term;
    #pragma unroll
    for (int mm = 1; mm < 64; mm <<= 1) dot += __shfl_xor(dot, mm);
    if (d == 0)
        scale[rel * N + i] = dot / (sqrtf(dga * dgb + 1e-8f) * 8.0f);  // sqrt(D)=8

    xr[w][d] = xsrc;
    __syncthreads();
    float o = bb[d];
    #pragma unroll 8
    for (int k = 0; k < D; ++k) o += xr[w][k] * Wl[d][k];
    Mt[((size_t)rel * D + d) * N + i] = f2bf(o);   // transposed, bf16
}

// ------------- Kernel B: fused online-softmax x (att @ M) via bf16 MFMA -------------
// grid (64 rowgroups, 3 rels, NSLICE j-slices), block = 256 (4 waves).
// Depth-2 register pipeline: prologue loads chunks 0,1; iter c re-issues c+2
// into buffer c&1 after consuming it -> loads get a full iteration of cover.
__global__ __launch_bounds__(256, 2) void attn_kernel(
    const float* __restrict__ S0, const float* __restrict__ S1, const float* __restrict__ S2,
    const float* __restrict__ scale, const unsigned short* __restrict__ Mt,
    unsigned short* __restrict__ Up, float* __restrict__ mp, float* __restrict__ lp)
{
    const int rg = blockIdx.x, rel = blockIdx.y, sl = blockIdx.z;
    const float* S = (rel == 0) ? S0 : (rel == 1 ? S1 : S2);
    const unsigned short* Mtr = Mt + (size_t)rel * D * N;
    const int tid = threadIdx.x;
    const int lane = tid & 63, wave = tid >> 6;
    const int row = tid >> 2, q = tid & 3;      // e-phase: 4 lanes per row

    // XOR-swizzled bf16 tiles: row stride 128B = 8 x 16B slots; slot ^= (row&7)
    __shared__ __align__(16) unsigned short E[64 * 64];
    __shared__ __align__(16) unsigned short Ml[64 * 64];
    __shared__ float scl_l[JLEN];
    __shared__ float aS[64];

    for (int k = tid; k < JLEN; k += 256)
        scl_l[k] = scale[rel * N + sl * JLEN + k];

    const float*          Sp = S   + (size_t)(rg * 64 + row) * N + sl * JLEN + q * 16;
    const unsigned short* Mp = Mtr + (size_t)row * N          + sl * JLEN + q * 16;

    char* Eb = (char*)E;
    char* Mb = (char*)Ml;
    const int sw  = (row & 7) << 4;
    const int ew0 = row * 128 + ((q * 32 +  0) ^ sw);
    const int ew1 = row * 128 + ((q * 32 + 16) ^ sw);

    float m = -INFINITY, l = 0.f;

    const int wbase = wave * 16;
    const int lrow  = lane & 15;   // A-row / B-col / C-col within tile
    const int lk    = lane >> 4;   // k-group / C row-group
    f32x4 acc[4];
    #pragma unroll
    for (int ct = 0; ct < 4; ++ct) {
        acc[ct][0] = 0.f; acc[ct][1] = 0.f; acc[ct][2] = 0.f; acc[ct][3] = 0.f;
    }

    float4 sv[2][4];
    uint4  mtv[2][2];
    // prologue: prefetch chunks 0 and 1
    #pragma unroll
    for (int b = 0; b < 2; ++b) {
        #pragma unroll
        for (int g = 0; g < 4; ++g)
            sv[b][g] = *(const float4*)(Sp + b * CH + g * 4);
        mtv[b][0] = *(const uint4*)(Mp + b * CH);
        mtv[b][1] = *(const uint4*)(Mp + b * CH + 8);
    }
    __syncthreads();   // scl_l visible

    #pragma unroll
    for (int c = 0; c < NCHUNK; ++c) {
        const int cb = c & 1;
        // ---- stage Mt(c) into swizzled LDS ----
        *(uint4*)(Mb + ew0) = mtv[cb][0];
        *(uint4*)(Mb + ew1) = mtv[cb][1];

        // ---- e-phase ----
        const float4 s0 = sv[cb][0], s1 = sv[cb][1], s2 = sv[cb][2], s3 = sv[cb][3];
        const float4 c0 = *(const float4*)&scl_l[c * 64 + q * 16 + 0];
        const float4 c1 = *(const float4*)&scl_l[c * 64 + q * 16 + 4];
        const float4 c2 = *(const float4*)&scl_l[c * 64 + q * 16 + 8];
        const float4 c3 = *(const float4*)&scl_l[c * 64 + q * 16 + 12];
        float lg[16];
        lg[0]=s0.x*c0.x; lg[1]=s0.y*c0.y; lg[2]=s0.z*c0.z; lg[3]=s0.w*c0.w;
        lg[4]=s1.x*c1.x; lg[5]=s1.y*c1.y; lg[6]=s1.z*c1.z; lg[7]=s1.w*c1.w;
        lg[8]=s2.x*c2.x; lg[9]=s2.y*c2.y; lg[10]=s2.z*c2.z; lg[11]=s2.w*c2.w;
        lg[12]=s3.x*c3.x; lg[13]=s3.y*c3.y; lg[14]=s3.z*c3.z; lg[15]=s3.w*c3.w;
        float cmax = lg[0];
        #pragma unroll
        for (int k = 1; k < 16; ++k) cmax = fmaxf(cmax, lg[k]);
        cmax = fmaxf(cmax, __shfl_xor(cmax, 1));
        cmax = fmaxf(cmax, __shfl_xor(cmax, 2));
        const float mn = fmaxf(m, cmax);
        const float al = __expf(m - mn);   // chunk 0: exp(-inf)=0
        float e[16], s = 0.f;
        #pragma unroll
        for (int k = 0; k < 16; ++k) { e[k] = __expf(lg[k] - mn); s += e[k]; }
        s += __shfl_xor(s, 1);
        s += __shfl_xor(s, 2);
        l = l * al + s; m = mn;
        if (q == 0) aS[row] = al;
        union { unsigned short h[8]; uint4 v; } p0, p1;
        #pragma unroll
        for (int k = 0; k < 8; ++k) { p0.h[k] = f2bf(e[k]); p1.h[k] = f2bf(e[8 + k]); }
        *(uint4*)(Eb + ew0) = p0.v;
        *(uint4*)(Eb + ew1) = p1.v;

        // ---- re-issue chunk c+2 into buffer cb (consumed; full-iteration cover) ----
        if (c + 2 < NCHUNK) {
            #pragma unroll
            for (int g = 0; g < 4; ++g)
                sv[cb][g] = *(const float4*)(Sp + (c + 2) * CH + g * 4);
            mtv[cb][0] = *(const uint4*)(Mp + (c + 2) * CH);
            mtv[cb][1] = *(const uint4*)(Mp + (c + 2) * CH + 8);
        }
        __syncthreads();

        // ---- rescale + MFMA ----
        const float av0 = aS[wbase + lk * 4 + 0];
        const float av1 = aS[wbase + lk * 4 + 1];
        const float av2 = aS[wbase + lk * 4 + 2];
        const float av3 = aS[wbase + lk * 4 + 3];
        #pragma unroll
        for (int ct = 0; ct < 4; ++ct) {
            acc[ct][0] *= av0; acc[ct][1] *= av1;
            acc[ct][2] *= av2; acc[ct][3] *= av3;
        }
        #pragma unroll
        for (int ks = 0; ks < 2; ++ks) {
            const int rowA  = wbase + lrow;
            const int slotA = (ks * 4 + lk) ^ (rowA & 7);
            const bf16x8 a  = *(const bf16x8*)(Eb + rowA * 128 + (slotA << 4));
            #pragma unroll
            for (int ct = 0; ct < 4; ++ct) {
                const int colB  = ct * 16 + lrow;
                const int slotB = (ks * 4 + lk) ^ (colB & 7);
                const bf16x8 b  = *(const bf16x8*)(Mb + colB * 128 + (slotB << 4));
                acc[ct] = __builtin_amdgcn_mfma_f32_16x16x32_bf16(a, b, acc[ct], 0, 0, 0);
            }
        }
        __syncthreads();   // before next chunk overwrites E/Ml/aS
    }

    // ---- repack partials into LDS (reuse E), then coalesced wide stores ----
    #pragma unroll
    for (int ct = 0; ct < 4; ++ct)
        #pragma unroll
        for (int r = 0; r < 4; ++r) {
            const int ri = wbase + lk * 4 + r;   // C/D: row=(lane>>4)*4+reg
            E[ri * 64 + ct * 16 + lrow] = f2bf(acc[ct][r]);
        }
    __syncthreads();
    const size_t pbase = (size_t)((rel * 64 + rg) * NSLICE + sl);
    unsigned short* up = Up + pbase * 4096;
    {
        const uint4* src = (const uint4*)((const char*)E + tid * 32);
        uint4*       dst = (uint4*)((char*)up + tid * 32);
        dst[0] = src[0];
        dst[1] = src[1];
    }
    if (q == 0) { mp[pbase * 64 + row] = m; lp[pbase * 64 + row] = l; }
}

// ---------------- Kernel C: combine partials + residual + linear(W3) + leaky-relu ----------------
__device__ __forceinline__ float combine_row(
    const unsigned short* __restrict__ Up, const float* __restrict__ mp,
    const float* __restrict__ lp, int rel, int i, int d)
{
    const int rg = i >> 6, r = i & 63;
    const int base = (rel * 64 + rg) * NSLICE;
    float mt = -INFINITY;
    #pragma unroll
    for (int p = 0; p < NSLICE; ++p) mt = fmaxf(mt, mp[(base + p) * 64 + r]);
    float lt = 0.f, u = 0.f;
    #pragma unroll
    for (int p = 0; p < NSLICE; ++p) {
        const float wgt = __expf(mp[(base + p) * 64 + r] - mt);
        lt += lp[(base + p) * 64 + r] * wgt;
        u  += bf2f(Up[(size_t)(base + p) * 4096 + r * 64 + d]) * wgt;
    }
    return u / lt;   // lt >= 1 for the max slice -> no div0
}

__global__ __launch_bounds__(256) void final_kernel(
    const float* __restrict__ embed,
    const unsigned short* __restrict__ Up, const float* __restrict__ mp,
    const float* __restrict__ lp,
    const float* __restrict__ W3, const float* __restrict__ b3,
    float* __restrict__ out)
{
    __shared__ float Wl[D][D + 1];
    __shared__ float xs[4][D];
    const int tid = threadIdx.x;
    for (int idx = tid; idx < D * D; idx += 256)
        Wl[idx >> 6][idx & 63] = W3[idx];
    const int w = tid >> 6, d = tid & 63;
    const int g = blockIdx.x * 4 + w;   // 0..8191

    float x = embed[(size_t)g * D + d];
    if (g < N) {
        x += combine_row(Up, mp, lp, 0, g, d);
        x += combine_row(Up, mp, lp, 1, g, d);
    } else {
        x += combine_row(Up, mp, lp, 2, g - N, d);
    }
    xs[w][d] = x;
    __syncthreads();
    float o = b3[d];
    #pragma unroll 8
    for (int k = 0; k < D; ++k) o += xs[w][k] * Wl[d][k];
    o = (o > 0.f) ? o : 0.2f * o;
    out[(size_t)g * D + d] = o;
}

extern "C" void kernel_launch(void* const* d_in, const int* in_sizes, int n_in,
                              void* d_out, int out_size, void* d_ws, size_t ws_size,
                              hipStream_t stream)
{
    const float* embed = (const float*)d_in[0];
    // d_in[1..3] = adj_* (unused by the reference)
    const float* Sc   = (const float*)d_in[4];
    const float* Si   = (const float*)d_in[5];
    const float* Ss   = (const float*)d_in[6];
    const float* degd = (const float*)d_in[7];
    const float* degt = (const float*)d_in[8];
    const float* W1 = (const float*)d_in[9];
    const float* b1 = (const float*)d_in[10];
    const float* W2 = (const float*)d_in[11];
    const float* b2 = (const float*)d_in[12];
    const float* W3 = (const float*)d_in[13];
    const float* b3 = (const float*)d_in[14];
    float* out = (float*)d_out;

    // ws layout:
    //   scale: 3*N              = 12288 f32
    //   mp:    3*64*NSLICE*64   = 98304 f32
    //   lp:                       98304 f32
    //   Mt:    3*D*N            = 786432 ushort
    //   Up:    3*64*NSLICE*4096 = 6291456 ushort          total ~15 MB
    float* ws    = (float*)d_ws;
    float* scale = ws;
    float* mp    = ws + 12288;
    float* lp    = mp + 98304;
    unsigned short* Mt = (unsigned short*)(lp + 98304);
    unsigned short* Up = Mt + 786432;

    prep_kernel<<<dim3(N / 4, 3), 256, 0, stream>>>(
        embed, degd, degt, W1, b1, W2, b2, W3, b3, scale, Mt);
    attn_kernel<<<dim3(64, 3, NSLICE), 256, 0, stream>>>(
        Sc, Si, Ss, scale, Mt, Up, mp, lp);
    final_kernel<<<dim3(2 * N / 4), 256, 0, stream>>>(
        embed, Up, mp, lp, W3, b3, out);
}